// Round 5
// baseline (132.563 us; speedup 1.0000x reference)
//
#include <hip/hip_runtime.h>

// Problem: B=128, V=1024, T=1024, C=1024
#define B_ 128
#define V_ 1024
#define T_ 1024
#define C_ 1024
#define KK 2048  // T_ + V_
#define NM 66    // M moments: p+q <= 10
#define NN 55    // N moments: p+q <= 9
#define SPLITK 32
#define KSLAB 64  // KK / SPLITK
#define KC 32     // LDS k-chunk in k3
#define CT 256    // c-tile
#define BT 64     // b-tile

// Degree-9 Taylor coefficients of f(s) = exp(tanh(s)).
constexpr float C9v[10] = {1.0f,          1.0f,          0.5f,
                           -0.166666667f, -0.291666667f, -0.025f,
                           0.134722222f,  0.054563493f,  -0.051165675f,
                           -0.041377307f};
constexpr float BN[11][11] = {
    {1, 0, 0, 0, 0, 0, 0, 0, 0, 0, 0},
    {1, 1, 0, 0, 0, 0, 0, 0, 0, 0, 0},
    {1, 2, 1, 0, 0, 0, 0, 0, 0, 0, 0},
    {1, 3, 3, 1, 0, 0, 0, 0, 0, 0, 0},
    {1, 4, 6, 4, 1, 0, 0, 0, 0, 0, 0},
    {1, 5, 10, 10, 5, 1, 0, 0, 0, 0, 0},
    {1, 6, 15, 20, 15, 6, 1, 0, 0, 0, 0},
    {1, 7, 21, 35, 35, 21, 7, 1, 0, 0, 0},
    {1, 8, 28, 56, 70, 56, 28, 8, 1, 0, 0},
    {1, 9, 36, 84, 126, 126, 84, 36, 9, 1, 0},
    {1, 10, 45, 120, 210, 252, 210, 120, 45, 10, 1}};

// kM: one wave per b. M[b][r] = sum_t w^p x^q  (p+q<=10).
// Single wave => butterfly happens once per block, not per 4 waves.
__global__ __launch_bounds__(64) void kM(const float* __restrict__ text,
                                         const float* __restrict__ w_vis,
                                         float* __restrict__ Mout) {
  const int b = blockIdx.x;
  const int lane = threadIdx.x;
  float mac[NM];
#pragma unroll
  for (int r = 0; r < NM; ++r) mac[r] = 0.f;
#pragma unroll
  for (int j = 0; j < 16; ++j) {
    const int t = lane + 64 * j;
    const float w = w_vis[t];
    const float x = text[b * T_ + t];
    float wp[11], xq[11];
    wp[0] = 1.f;
    xq[0] = 1.f;
#pragma unroll
    for (int k = 1; k <= 10; ++k) {
      wp[k] = wp[k - 1] * w;
      xq[k] = xq[k - 1] * x;
    }
#pragma unroll
    for (int i = 0; i <= 10; ++i)
#pragma unroll
      for (int p = 0; p <= i; ++p)
        mac[i * (i + 1) / 2 + p] =
            fmaf(wp[p], xq[i - p], mac[i * (i + 1) / 2 + p]);
  }
#pragma unroll
  for (int m = 1; m <= 32; m <<= 1)
#pragma unroll
    for (int r = 0; r < NM; ++r) mac[r] += __shfl_xor(mac[r], m, 64);
  if (lane == 0) {
#pragma unroll
    for (int r = 0; r < NM; ++r) Mout[b * NM + r] = mac[r];
  }
}

// kA: one block per b, 256 threads, 4 v's per thread.
// Per v: T1 = sum h*M (denom), T2 = sum h*M_shift (e*x sum);
// text_score = T2/T1 -> St; nac += h * (al/T1). M read via uniform
// pointer -> SGPR s_loads (no VGPR cost). h recomputed, never stored.
__global__ __launch_bounds__(256) void kA(const float* __restrict__ visual,
                                          const float* __restrict__ w_text,
                                          const float* __restrict__ bias,
                                          const float* __restrict__ Min,
                                          float* __restrict__ St,
                                          float* __restrict__ Nout) {
  const int b = blockIdx.x;
  const int tid = threadIdx.x;
  const int lane = tid & 63, wave = tid >> 6;
  const float* __restrict__ M = Min + b * NM;  // wave-uniform
  float nac[NN];
#pragma unroll
  for (int r = 0; r < NN; ++r) nac[r] = 0.f;
#pragma unroll
  for (int j = 0; j < 4; ++j) {
    const int v = tid + 256 * j;
    const float al = visual[b * V_ + v];
    const float be = w_text[v];
    const float ga = bias[v];
    float ap[10], bq[10];
    ap[0] = 1.f;
    bq[0] = 1.f;
#pragma unroll
    for (int k = 1; k <= 9; ++k) {
      ap[k] = ap[k - 1] * al;
      bq[k] = bq[k - 1] * be;
    }
    float d[10];
#pragma unroll
    for (int i = 0; i < 10; ++i) {
      float a = 0.f;
#pragma unroll
      for (int jj = 9; jj >= i; --jj) a = fmaf(a, ga, C9v[jj] * BN[jj][i]);
      d[i] = a;
    }
    float T1 = 0.f, T2 = 0.f;
#pragma unroll
    for (int i = 0; i <= 9; ++i)
#pragma unroll
      for (int p = 0; p <= i; ++p) {
        const int ix = i * (i + 1) / 2 + p;
        const int ix2 = (i + 1) * (i + 2) / 2 + p;
        const float t2 = (BN[i][p] * ap[p]) * bq[i - p];
        const float h = t2 * d[i];
        T1 = fmaf(h, M[ix], T1);
        T2 = fmaf(h, M[ix2], T2);
      }
    const float rd = 1.0f / T1;
    St[(T_ + v) * B_ + b] = T2 * rd;  // text_score, k-major
    const float vr = al * rd;
    float e[10];
#pragma unroll
    for (int i = 0; i < 10; ++i) e[i] = d[i] * vr;
#pragma unroll
    for (int i = 0; i <= 9; ++i)
#pragma unroll
      for (int p = 0; p <= i; ++p) {
        const int ix = i * (i + 1) / 2 + p;
        const float t2 = (BN[i][p] * ap[p]) * bq[i - p];
        nac[ix] = fmaf(e[i], t2, nac[ix]);
      }
  }
#pragma unroll
  for (int m = 1; m <= 32; m <<= 1)
#pragma unroll
    for (int r = 0; r < NN; ++r) nac[r] += __shfl_xor(nac[r], m, 64);
  __shared__ float Rw[4][NN];
  if (lane == 0) {
#pragma unroll
    for (int r = 0; r < NN; ++r) Rw[wave][r] = nac[r];
  }
  __syncthreads();
  if (tid < NN)
    Nout[b * NN + tid] =
        (Rw[0][tid] + Rw[1][tid]) + (Rw[2][tid] + Rw[3][tid]);
}

// kB: visual_score[b,t] = sum_{p,q} w^p x^q N[b][p,q]. 2 blocks per b.
// N via uniform pointer -> SGPR s_loads.
__global__ __launch_bounds__(256) void kB(const float* __restrict__ text,
                                          const float* __restrict__ w_vis,
                                          const float* __restrict__ Nin,
                                          float* __restrict__ St) {
  const int b = blockIdx.x >> 1;
  const int half = blockIdx.x & 1;
  const float* __restrict__ N = Nin + b * NN;  // uniform
#pragma unroll
  for (int j = 0; j < 2; ++j) {
    const int t = half * 512 + (int)threadIdx.x + 256 * j;
    const float w = w_vis[t];
    const float x = text[b * T_ + t];
    float wp[10], xq[10];
    wp[0] = 1.f;
    xq[0] = 1.f;
#pragma unroll
    for (int k = 1; k <= 9; ++k) {
      wp[k] = wp[k - 1] * w;
      xq[k] = xq[k - 1] * x;
    }
    float vs = 0.f;
#pragma unroll
    for (int i = 0; i <= 9; ++i)
#pragma unroll
      for (int p = 0; p <= i; ++p)
        vs = fmaf(wp[p] * xq[i - p], N[i * (i + 1) / 2 + p], vs);
    St[t * B_ + b] = vs;  // k-major
  }
}

// k3: split-K GEMM. part[z][b][c] = sum_{k in slab z} St[k][b]*Wcat[c][k].
// Tile 64b x 256c, micro 8x8 (64 FMA per 2 ds_read_b128 -> VALU-bound).
// St read straight from global (wave-broadcast, L2-hot); only W in LDS.
// Grid (4,2,32) = 256 blocks = 1/CU, 4 waves fill all SIMDs.
__global__ __launch_bounds__(256) void k3_gemm(const float* __restrict__ St,
                                               const float* __restrict__ W_fv,
                                               const float* __restrict__ W_ft,
                                               float* __restrict__ part) {
  __shared__ float Ws[KC][CT];  // 32 KB
  const int cb = blockIdx.x * CT;
  const int bb = blockIdx.y * BT;
  const int ks = blockIdx.z * KSLAB;
  const float* __restrict__ W = (ks < T_) ? (W_fv + ks) : (W_ft + (ks - T_));
  const int tid = threadIdx.x;
  const int bg = tid & 7, cg = tid >> 3;      // compute micro-tile coords
  const int kq = tid & 7, cr0 = tid >> 3;     // staging coords
  float acc[8][8];
#pragma unroll
  for (int i = 0; i < 8; ++i)
#pragma unroll
    for (int j = 0; j < 8; ++j) acc[i][j] = 0.f;

  for (int kk = 0; kk < KSLAB; kk += KC) {
    // stage 32k x 256c of W, transposed: 8 passes of 32 c-rows, 128B/row
#pragma unroll
    for (int pass = 0; pass < 8; ++pass) {
      const int c = cr0 + 32 * pass;
      float4 g = *(const float4*)&W[(cb + c) * 1024 + kk + 4 * kq];
      Ws[4 * kq + 0][c] = g.x;
      Ws[4 * kq + 1][c] = g.y;
      Ws[4 * kq + 2][c] = g.z;
      Ws[4 * kq + 3][c] = g.w;
    }
    __syncthreads();
    const float* __restrict__ Srow = St + (size_t)(ks + kk) * B_ + bb + 8 * bg;
#pragma unroll 4
    for (int k = 0; k < KC; ++k) {
      const float4 s0 = *(const float4*)&Srow[k * B_];
      const float4 s1 = *(const float4*)&Srow[k * B_ + 4];
      const float4 w0 = *(const float4*)&Ws[k][8 * cg];
      const float4 w1 = *(const float4*)&Ws[k][8 * cg + 4];
      const float s[8] = {s0.x, s0.y, s0.z, s0.w, s1.x, s1.y, s1.z, s1.w};
      const float w[8] = {w0.x, w0.y, w0.z, w0.w, w1.x, w1.y, w1.z, w1.w};
#pragma unroll
      for (int i = 0; i < 8; ++i)
#pragma unroll
        for (int j = 0; j < 8; ++j) acc[i][j] = fmaf(s[i], w[j], acc[i][j]);
    }
    __syncthreads();
  }
  float* __restrict__ P = part + (size_t)blockIdx.z * (B_ * C_);
#pragma unroll
  for (int i = 0; i < 8; ++i) {
    float4 o0 = make_float4(acc[i][0], acc[i][1], acc[i][2], acc[i][3]);
    float4 o1 = make_float4(acc[i][4], acc[i][5], acc[i][6], acc[i][7]);
    float* row = &P[(bb + 8 * bg + i) * C_ + cb + 8 * cg];
    *(float4*)&row[0] = o0;
    *(float4*)&row[4] = o1;
  }
}

// k4: out[i] = relu(sum_z part[z][i] + b_fv[c] + b_ft[c]), float4-wide.
__global__ __launch_bounds__(256) void k4_reduce_biasrelu(
    const float* __restrict__ part, const float* __restrict__ b_fv,
    const float* __restrict__ b_ft, float* __restrict__ out) {
  const int i4 = (blockIdx.x * 256 + threadIdx.x) * 4;
  float sx = 0.f, sy = 0.f, sz = 0.f, sw = 0.f;
#pragma unroll
  for (int z = 0; z < SPLITK; ++z) {
    float4 p = *(const float4*)&part[(size_t)z * (B_ * C_) + i4];
    sx += p.x;
    sy += p.y;
    sz += p.z;
    sw += p.w;
  }
  const int c = i4 & (C_ - 1);
  float4 bf = *(const float4*)&b_fv[c];
  float4 bt = *(const float4*)&b_ft[c];
  float4 o;
  o.x = fmaxf(sx + bf.x + bt.x, 0.f);
  o.y = fmaxf(sy + bf.y + bt.y, 0.f);
  o.z = fmaxf(sz + bf.z + bt.z, 0.f);
  o.w = fmaxf(sw + bf.w + bt.w, 0.f);
  *(float4*)&out[i4] = o;
}

extern "C" void kernel_launch(void* const* d_in, const int* in_sizes, int n_in,
                              void* d_out, int out_size, void* d_ws, size_t ws_size,
                              hipStream_t stream) {
  const float* visual = (const float*)d_in[0];  // [B,V]
  const float* text   = (const float*)d_in[1];  // [B,T]
  const float* w_vis  = (const float*)d_in[2];  // [T]
  const float* w_text = (const float*)d_in[3];  // [V]
  const float* bias   = (const float*)d_in[4];  // [V]
  const float* W_fv   = (const float*)d_in[5];  // [C,T]
  const float* b_fv   = (const float*)d_in[6];  // [C]
  const float* W_ft   = (const float*)d_in[7];  // [C,V]
  const float* b_ft   = (const float*)d_in[8];  // [C]
  float* out = (float*)d_out;                   // [B,C]

  // ws (floats): St[2048*128] | M[128*66] | N[128*55] | part[32][B*C]
  float* St = (float*)d_ws;
  float* M = St + (size_t)KK * B_;
  float* N = M + B_ * NM;
  float* part = N + B_ * NN;

  kM<<<dim3(B_), dim3(64), 0, stream>>>(text, w_vis, M);
  kA<<<dim3(B_), dim3(256), 0, stream>>>(visual, w_text, bias, M, St, N);
  kB<<<dim3(B_ * 2), dim3(256), 0, stream>>>(text, w_vis, N, St);
  k3_gemm<<<dim3(C_ / CT, B_ / BT, SPLITK), dim3(256), 0, stream>>>(
      St, W_fv, W_ft, part);
  k4_reduce_biasrelu<<<dim3(B_ * C_ / 1024), dim3(256), 0, stream>>>(
      part, b_fv, b_ft, out);
}

// Round 6
// 119.092 us; speedup vs baseline: 1.1131x; 1.1131x over previous
//
#include <hip/hip_runtime.h>

// Problem: B=128, V=1024, T=1024, C=1024
#define B_ 128
#define V_ 1024
#define T_ 1024
#define C_ 1024
#define KK 2048  // T_ + V_
#define NM 66    // M moments: p+q <= 10
#define NN 55    // N moments: p+q <= 9
#define SPLITK 32
#define KSLAB 64  // KK / SPLITK
#define KC 32     // LDS k-chunk in k3

// Degree-9 Taylor coefficients of f(s) = exp(tanh(s)).
constexpr float C9v[10] = {1.0f,          1.0f,          0.5f,
                           -0.166666667f, -0.291666667f, -0.025f,
                           0.134722222f,  0.054563493f,  -0.051165675f,
                           -0.041377307f};
constexpr float BN[11][11] = {
    {1, 0, 0, 0, 0, 0, 0, 0, 0, 0, 0},
    {1, 1, 0, 0, 0, 0, 0, 0, 0, 0, 0},
    {1, 2, 1, 0, 0, 0, 0, 0, 0, 0, 0},
    {1, 3, 3, 1, 0, 0, 0, 0, 0, 0, 0},
    {1, 4, 6, 4, 1, 0, 0, 0, 0, 0, 0},
    {1, 5, 10, 10, 5, 1, 0, 0, 0, 0, 0},
    {1, 6, 15, 20, 15, 6, 1, 0, 0, 0, 0},
    {1, 7, 21, 35, 35, 21, 7, 1, 0, 0, 0},
    {1, 8, 28, 56, 70, 56, 28, 8, 1, 0, 0},
    {1, 9, 36, 84, 126, 126, 84, 36, 9, 1, 0},
    {1, 10, 45, 120, 210, 252, 210, 120, 45, 10, 1}};

// kM: 2 blocks per b (256 blocks). Mpart[2b+half][r] = sum_{t in half} w^p x^q.
__global__ __launch_bounds__(256) void kM(const float* __restrict__ text,
                                          const float* __restrict__ w_vis,
                                          float* __restrict__ Mpart) {
  const int b = blockIdx.x >> 1, half = blockIdx.x & 1;
  const int tid = threadIdx.x;
  const int lane = tid & 63, wave = tid >> 6;
  float mac[NM];
#pragma unroll
  for (int r = 0; r < NM; ++r) mac[r] = 0.f;
#pragma unroll
  for (int j = 0; j < 2; ++j) {
    const int t = half * 512 + tid + 256 * j;
    const float w = w_vis[t];
    const float x = text[b * T_ + t];
    float wp[11], xq[11];
    wp[0] = 1.f;
    xq[0] = 1.f;
#pragma unroll
    for (int k = 1; k <= 10; ++k) {
      wp[k] = wp[k - 1] * w;
      xq[k] = xq[k - 1] * x;
    }
#pragma unroll
    for (int i = 0; i <= 10; ++i)
#pragma unroll
      for (int p = 0; p <= i; ++p)
        mac[i * (i + 1) / 2 + p] =
            fmaf(wp[p], xq[i - p], mac[i * (i + 1) / 2 + p]);
  }
#pragma unroll
  for (int m = 1; m <= 32; m <<= 1)
#pragma unroll
    for (int r = 0; r < NM; ++r) mac[r] += __shfl_xor(mac[r], m, 64);
  __shared__ float Rw[4][NM];
  if (lane == 0) {
#pragma unroll
    for (int r = 0; r < NM; ++r) Rw[wave][r] = mac[r];
  }
  __syncthreads();
  if (tid < NM)
    Mpart[(size_t)blockIdx.x * NM + tid] =
        (Rw[0][tid] + Rw[1][tid]) + (Rw[2][tid] + Rw[3][tid]);
}

// kA: 2 blocks per b (256 blocks), 2 v's/thread. M = Mpart[2b]+Mpart[2b+1]
// via uniform s_loads. text_score -> St[b][1024+v] (b-major, coalesced);
// Npart[2b+half][r] partial v-moments.
__global__ __launch_bounds__(256) void kA(const float* __restrict__ visual,
                                          const float* __restrict__ w_text,
                                          const float* __restrict__ bias,
                                          const float* __restrict__ Mpart,
                                          float* __restrict__ St,
                                          float* __restrict__ Npart) {
  const int b = blockIdx.x >> 1, half = blockIdx.x & 1;
  const int tid = threadIdx.x;
  const int lane = tid & 63, wave = tid >> 6;
  const float* __restrict__ M0 = Mpart + (size_t)(2 * b) * NM;  // uniform
  const float* __restrict__ M1 = M0 + NM;
  float nac[NN];
#pragma unroll
  for (int r = 0; r < NN; ++r) nac[r] = 0.f;
#pragma unroll
  for (int j = 0; j < 2; ++j) {
    const int v = half * 512 + tid + 256 * j;
    const float al = visual[b * V_ + v];
    const float be = w_text[v];
    const float ga = bias[v];
    float ap[10], bq[10];
    ap[0] = 1.f;
    bq[0] = 1.f;
#pragma unroll
    for (int k = 1; k <= 9; ++k) {
      ap[k] = ap[k - 1] * al;
      bq[k] = bq[k - 1] * be;
    }
    float d[10];
#pragma unroll
    for (int i = 0; i < 10; ++i) {
      float a = 0.f;
#pragma unroll
      for (int jj = 9; jj >= i; --jj) a = fmaf(a, ga, C9v[jj] * BN[jj][i]);
      d[i] = a;
    }
    float T1 = 0.f, T2 = 0.f;
#pragma unroll
    for (int i = 0; i <= 9; ++i)
#pragma unroll
      for (int p = 0; p <= i; ++p) {
        const int ix = i * (i + 1) / 2 + p;
        const int ix2 = (i + 1) * (i + 2) / 2 + p;
        const float t2 = (BN[i][p] * ap[p]) * bq[i - p];
        const float h = t2 * d[i];
        T1 = fmaf(h, M0[ix] + M1[ix], T1);
        T2 = fmaf(h, M0[ix2] + M1[ix2], T2);
      }
    const float rd = 1.0f / T1;
    St[b * KK + T_ + v] = T2 * rd;  // b-major, coalesced
    const float vr = al * rd;
    float e[10];
#pragma unroll
    for (int i = 0; i < 10; ++i) e[i] = d[i] * vr;
#pragma unroll
    for (int i = 0; i <= 9; ++i)
#pragma unroll
      for (int p = 0; p <= i; ++p) {
        const int ix = i * (i + 1) / 2 + p;
        const float t2 = (BN[i][p] * ap[p]) * bq[i - p];
        nac[ix] = fmaf(e[i], t2, nac[ix]);
      }
  }
#pragma unroll
  for (int m = 1; m <= 32; m <<= 1)
#pragma unroll
    for (int r = 0; r < NN; ++r) nac[r] += __shfl_xor(nac[r], m, 64);
  __shared__ float Rw[4][NN];
  if (lane == 0) {
#pragma unroll
    for (int r = 0; r < NN; ++r) Rw[wave][r] = nac[r];
  }
  __syncthreads();
  if (tid < NN)
    Npart[(size_t)blockIdx.x * NN + tid] =
        (Rw[0][tid] + Rw[1][tid]) + (Rw[2][tid] + Rw[3][tid]);
}

// kB: visual_score[b,t] = sum_r (w^p x^q) N[b][r], N = Npart[2b]+Npart[2b+1].
// 2 blocks per b; stores b-major (coalesced).
__global__ __launch_bounds__(256) void kB(const float* __restrict__ text,
                                          const float* __restrict__ w_vis,
                                          const float* __restrict__ Npart,
                                          float* __restrict__ St) {
  const int b = blockIdx.x >> 1, half = blockIdx.x & 1;
  const float* __restrict__ N0 = Npart + (size_t)(2 * b) * NN;  // uniform
  const float* __restrict__ N1 = N0 + NN;
#pragma unroll
  for (int j = 0; j < 2; ++j) {
    const int t = half * 512 + (int)threadIdx.x + 256 * j;
    const float w = w_vis[t];
    const float x = text[b * T_ + t];
    float wp[10], xq[10];
    wp[0] = 1.f;
    xq[0] = 1.f;
#pragma unroll
    for (int k = 1; k <= 9; ++k) {
      wp[k] = wp[k - 1] * w;
      xq[k] = xq[k - 1] * x;
    }
    float vs = 0.f;
#pragma unroll
    for (int i = 0; i <= 9; ++i)
#pragma unroll
      for (int p = 0; p <= i; ++p) {
        const int ix = i * (i + 1) / 2 + p;
        vs = fmaf(wp[p] * xq[i - p], N0[ix] + N1[ix], vs);
      }
    St[b * KK + t] = vs;  // b-major, coalesced
  }
}

// k3: split-K fp32 GEMM, both operands in LDS, micro 8x8.
// part[z][b][c] = sum_{k in slab z} St[b][k] * Wcat[c][k].
// Tile 64b x 256c, slab 64k (2 chunks of KC=32). Grid (4,2,32)=256 blocks.
__global__ __launch_bounds__(256) void k3_gemm(const float* __restrict__ St,
                                               const float* __restrict__ W_fv,
                                               const float* __restrict__ W_ft,
                                               float* __restrict__ part) {
  __shared__ float Ss[KC][68];   // [k][b]  (transposed at staging)
  __shared__ float Ws[KC][260];  // [k][c]  (transposed at staging)
  const int cb = blockIdx.x * 256;
  const int bb = blockIdx.y * 64;
  const int ks = blockIdx.z * KSLAB;
  const int koff = (ks < T_) ? ks : (ks - T_);
  const float* __restrict__ W = (ks < T_) ? W_fv : W_ft;
  const int tid = threadIdx.x;
  const int bg = tid >> 5, cg = tid & 31;  // compute: 8 b's x 8 c's
  const int kq = tid & 7, rr = tid >> 3;   // staging
  float acc[8][8];
#pragma unroll
  for (int i = 0; i < 8; ++i)
#pragma unroll
    for (int j = 0; j < 8; ++j) acc[i][j] = 0.f;

  for (int kk = 0; kk < KSLAB; kk += KC) {
    // St chunk: 32k x 64b. Coalesced global float4 along k; transpose to LDS.
#pragma unroll
    for (int pass = 0; pass < 2; ++pass) {
      const int row = rr + 32 * pass;  // b-row
      float4 g = *(const float4*)&St[(bb + row) * KK + ks + kk + 4 * kq];
      Ss[4 * kq + 0][row] = g.x;
      Ss[4 * kq + 1][row] = g.y;
      Ss[4 * kq + 2][row] = g.z;
      Ss[4 * kq + 3][row] = g.w;
    }
    // W chunk: 32k x 256c. 4 rows per thread -> transposed float4 writes.
#pragma unroll
    for (int pass = 0; pass < 2; ++pass) {
      const int c0 = 4 * rr + 128 * pass;
      const float* wr = &W[(size_t)(cb + c0) * 1024 + koff + kk + 4 * kq];
      float4 g0 = *(const float4*)&wr[0];
      float4 g1 = *(const float4*)&wr[1024];
      float4 g2 = *(const float4*)&wr[2048];
      float4 g3 = *(const float4*)&wr[3072];
      *(float4*)&Ws[4 * kq + 0][c0] = make_float4(g0.x, g1.x, g2.x, g3.x);
      *(float4*)&Ws[4 * kq + 1][c0] = make_float4(g0.y, g1.y, g2.y, g3.y);
      *(float4*)&Ws[4 * kq + 2][c0] = make_float4(g0.z, g1.z, g2.z, g3.z);
      *(float4*)&Ws[4 * kq + 3][c0] = make_float4(g0.w, g1.w, g2.w, g3.w);
    }
    __syncthreads();
#pragma unroll 8
    for (int k = 0; k < KC; ++k) {
      const float4 s0 = *(const float4*)&Ss[k][8 * bg];
      const float4 s1 = *(const float4*)&Ss[k][8 * bg + 4];
      const float4 w0 = *(const float4*)&Ws[k][8 * cg];
      const float4 w1 = *(const float4*)&Ws[k][8 * cg + 4];
      const float s[8] = {s0.x, s0.y, s0.z, s0.w, s1.x, s1.y, s1.z, s1.w};
      const float w[8] = {w0.x, w0.y, w0.z, w0.w, w1.x, w1.y, w1.z, w1.w};
#pragma unroll
      for (int i = 0; i < 8; ++i)
#pragma unroll
        for (int j = 0; j < 8; ++j) acc[i][j] = fmaf(s[i], w[j], acc[i][j]);
    }
    __syncthreads();
  }
  float* __restrict__ P = part + (size_t)blockIdx.z * (B_ * C_);
#pragma unroll
  for (int i = 0; i < 8; ++i) {
    float* row = &P[(bb + 8 * bg + i) * C_ + cb + 8 * cg];
    *(float4*)&row[0] = make_float4(acc[i][0], acc[i][1], acc[i][2], acc[i][3]);
    *(float4*)&row[4] = make_float4(acc[i][4], acc[i][5], acc[i][6], acc[i][7]);
  }
}

// k4: out[i] = relu(sum_z part[z][i] + b_fv[c] + b_ft[c]), float4-wide.
__global__ __launch_bounds__(256) void k4_reduce_biasrelu(
    const float* __restrict__ part, const float* __restrict__ b_fv,
    const float* __restrict__ b_ft, float* __restrict__ out) {
  const int i4 = (blockIdx.x * 256 + threadIdx.x) * 4;
  float sx = 0.f, sy = 0.f, sz = 0.f, sw = 0.f;
#pragma unroll
  for (int z = 0; z < SPLITK; ++z) {
    float4 p = *(const float4*)&part[(size_t)z * (B_ * C_) + i4];
    sx += p.x;
    sy += p.y;
    sz += p.z;
    sw += p.w;
  }
  const int c = i4 & (C_ - 1);
  float4 bf = *(const float4*)&b_fv[c];
  float4 bt = *(const float4*)&b_ft[c];
  float4 o;
  o.x = fmaxf(sx + bf.x + bt.x, 0.f);
  o.y = fmaxf(sy + bf.y + bt.y, 0.f);
  o.z = fmaxf(sz + bf.z + bt.z, 0.f);
  o.w = fmaxf(sw + bf.w + bt.w, 0.f);
  *(float4*)&out[i4] = o;
}

extern "C" void kernel_launch(void* const* d_in, const int* in_sizes, int n_in,
                              void* d_out, int out_size, void* d_ws, size_t ws_size,
                              hipStream_t stream) {
  const float* visual = (const float*)d_in[0];  // [B,V]
  const float* text   = (const float*)d_in[1];  // [B,T]
  const float* w_vis  = (const float*)d_in[2];  // [T]
  const float* w_text = (const float*)d_in[3];  // [V]
  const float* bias   = (const float*)d_in[4];  // [V]
  const float* W_fv   = (const float*)d_in[5];  // [C,T]
  const float* b_fv   = (const float*)d_in[6];  // [C]
  const float* W_ft   = (const float*)d_in[7];  // [C,V]
  const float* b_ft   = (const float*)d_in[8];  // [C]
  float* out = (float*)d_out;                   // [B,C]

  // ws (floats): St[B][2048] | Mpart[256][66] | Npart[256][55] | part[32][B*C]
  float* St = (float*)d_ws;
  float* Mpart = St + (size_t)B_ * KK;
  float* Npart = Mpart + 256 * NM;
  float* part = Npart + 256 * NN;

  kM<<<dim3(B_ * 2), dim3(256), 0, stream>>>(text, w_vis, Mpart);
  kA<<<dim3(B_ * 2), dim3(256), 0, stream>>>(visual, w_text, bias, Mpart, St,
                                             Npart);
  kB<<<dim3(B_ * 2), dim3(256), 0, stream>>>(text, w_vis, Npart, St);
  k3_gemm<<<dim3(C_ / 256, B_ / 64, SPLITK), dim3(256), 0, stream>>>(
      St, W_fv, W_ft, part);
  k4_reduce_biasrelu<<<dim3(B_ * C_ / 1024), dim3(256), 0, stream>>>(
      part, b_fv, b_ft, out);
}